// Round 12
// baseline (1032.528 us; speedup 1.0000x reference)
//
#include <hip/hip_runtime.h>

typedef float f32x4 __attribute__((ext_vector_type(4)));
typedef _Float16 f16x8 __attribute__((ext_vector_type(8)));
typedef _Float16 f16x4 __attribute__((ext_vector_type(4)));

constexpr int kB = 128;     // batch
constexpr int kT = 512;     // time
constexpr int kD = 256;     // emb dim
constexpr int kG = 512;     // 4*H gates per direction
constexpr int kH = 128;     // hidden
constexpr int kK = 9;       // CRF states
constexpr int kSTART = 7;
constexpr int kSTOP = 8;
constexpr int kNB = 16;     // chains per LSTM workgroup

#if defined(__has_attribute)
#if __has_attribute(amdgpu_waves_per_eu)
#define WAVES_EU_2 __attribute__((amdgpu_waves_per_eu(2, 2)))
#else
#define WAVES_EU_2
#endif
#else
#define WAVES_EU_2
#endif

// gi layout, f16:  [dirg = dir*8+g][t][q(4)][u(128)][r(16)]; row = 8192 f16.
// proj ZERO-FILLS gi for t >= len[chain] -> lstm needs no length masking.
// hws (h output) aliases gi row head [0,2048): stores trail consumption.
// Prefetch overruns (fwd up, bwd down, +-2 rows) stay inside the gi region.

// ---------------------------------------------------------------------------
// Kernel 1: embedding gather + input projection (f16 MFMA GEMM)  [unchanged]
// ---------------------------------------------------------------------------
__global__ __launch_bounds__(256) void proj_kernel(
    const int* __restrict__ sentence, const int* __restrict__ lengths,
    const float* __restrict__ emb,
    const float* __restrict__ Wih_f, const float* __restrict__ b_f,
    const float* __restrict__ Wih_b, const float* __restrict__ b_b,
    _Float16* __restrict__ gi)
{
    __shared__ __align__(16) _Float16 smemA[128 * 256]; // rows=(t,chain), 512B
    __shared__ __align__(16) _Float16 smemW[128 * 256]; // rows=gate, 512B

    const int g  = blockIdx.x >> 6;
    const int tc = blockIdx.x & 63;
    if (tc * 8 >= lengths[g * 16]) return;   // whole 8-t chunk beyond group max
    const int tid = threadIdx.x;

    // ---- stage A once: row = t_local*16 + chain ----
    {
        const int row = tid >> 1;
        const int kb  = (tid & 1) << 7;
        const int b   = g * 16 + (row & 15);
        const int t   = tc * 8 + (row >> 4);
        const int vocab = sentence[b * kT + t];
        const float* src = emb + (size_t)vocab * kD + kb;
        const unsigned rowbyte = row * 512;
        const unsigned sw = (row & 7) << 4;
        #pragma unroll
        for (int c = 0; c < 16; ++c) {
            float4 x0 = *(const float4*)(src + c * 8);
            float4 x1 = *(const float4*)(src + c * 8 + 4);
            f16x8 pk;
            pk[0] = (_Float16)x0.x; pk[1] = (_Float16)x0.y;
            pk[2] = (_Float16)x0.z; pk[3] = (_Float16)x0.w;
            pk[4] = (_Float16)x1.x; pk[5] = (_Float16)x1.y;
            pk[6] = (_Float16)x1.z; pk[7] = (_Float16)x1.w;
            unsigned byteoff = rowbyte + ((unsigned)((kb + c * 8) * 2) ^ sw);
            *(f16x8*)((char*)smemA + byteoff) = pk;
        }
    }

    const int w    = tid >> 6;
    const int lane = tid & 63;
    const int wr = w >> 1, wc = w & 1;
    const int l15 = lane & 15, l4 = lane >> 4;

    int lene[4];
    #pragma unroll
    for (int rg = 0; rg < 4; ++rg)
        lene[rg] = lengths[g * 16 + l4 * 4 + rg];

    for (int by = 0; by < 8; ++by) {
        const int dir = by >> 2;
        const int q   = by & 3;
        __syncthreads();
        {
            const int row = tid >> 1;
            const int kb  = (tid & 1) << 7;
            const float* src = (dir == 0 ? Wih_f : Wih_b)
                               + (size_t)(q * 128 + row) * kD + kb;
            const unsigned rowbyte = row * 512;
            const unsigned sw = (row & 7) << 4;
            #pragma unroll
            for (int c = 0; c < 16; ++c) {
                float4 x0 = *(const float4*)(src + c * 8);
                float4 x1 = *(const float4*)(src + c * 8 + 4);
                f16x8 pk;
                pk[0] = (_Float16)x0.x; pk[1] = (_Float16)x0.y;
                pk[2] = (_Float16)x0.z; pk[3] = (_Float16)x0.w;
                pk[4] = (_Float16)x1.x; pk[5] = (_Float16)x1.y;
                pk[6] = (_Float16)x1.z; pk[7] = (_Float16)x1.w;
                unsigned byteoff = rowbyte + ((unsigned)((kb + c * 8) * 2) ^ sw);
                *(f16x8*)((char*)smemW + byteoff) = pk;
            }
        }
        __syncthreads();

        f32x4 zero = {0.f, 0.f, 0.f, 0.f};
        f32x4 acc[4][4];
        #pragma unroll
        for (int mf = 0; mf < 4; ++mf)
            #pragma unroll
            for (int nf = 0; nf < 4; ++nf) acc[mf][nf] = zero;

        #pragma unroll
        for (int kk = 0; kk < 8; ++kk) {
            f16x8 afr[4], bfr[4];
            #pragma unroll
            for (int mf = 0; mf < 4; ++mf) {
                int row = wr * 64 + mf * 16 + l15;
                unsigned byteoff = row * 512 +
                    ((unsigned)(kk * 64 + l4 * 16) ^ (unsigned)((row & 7) << 4));
                afr[mf] = *(const f16x8*)((const char*)smemA + byteoff);
            }
            #pragma unroll
            for (int nf = 0; nf < 4; ++nf) {
                int row = wc * 64 + nf * 16 + l15;
                unsigned byteoff = row * 512 +
                    ((unsigned)(kk * 64 + l4 * 16) ^ (unsigned)((row & 7) << 4));
                bfr[nf] = *(const f16x8*)((const char*)smemW + byteoff);
            }
            #pragma unroll
            for (int mf = 0; mf < 4; ++mf)
                #pragma unroll
                for (int nf = 0; nf < 4; ++nf)
                    acc[mf][nf] = __builtin_amdgcn_mfma_f32_16x16x32_f16(
                        afr[mf], bfr[nf], acc[mf][nf], 0, 0, 0);
        }

        const float* biasp = (dir == 0) ? b_f : b_b;
        _Float16* dbase = gi + (size_t)(dir * 8 + g) * kT * 8192;
        #pragma unroll
        for (int nf = 0; nf < 4; ++nf) {
            int u = wc * 64 + nf * 16 + l15;
            float bias = biasp[q * 128 + u];
            #pragma unroll
            for (int mf = 0; mf < 4; ++mf) {
                int t = tc * 8 + wr * 4 + mf;
                f16x4 pk;
                #pragma unroll
                for (int rg = 0; rg < 4; ++rg) {
                    float v = (t < lene[rg]) ? (acc[mf][nf][rg] + bias) : 0.f;
                    pk[rg] = (_Float16)v;
                }
                *(f16x4*)(dbase + (size_t)t * 8192 + (q * 128 + u) * 16 + l4 * 4) = pk;
            }
        }
    }
}

// ---------------------------------------------------------------------------
// Kernel 2: persistent weight-stationary LSTM, BOTH DIRS PER WG.
// 8 wgs x 512 thr; per superstep each thread advances fwd AND bwd chains.
// amdgpu_waves_per_eu(2,2): pin allocator target to 2 waves/EU (the only
// feasible occupancy: 8 waves, 1 wg/CU) -> 256-VGPR budget, no spill of the
// 128-VGPR dual weight set. launch_bounds(512,2) alone did NOT do this
// (R11: VGPR stayed 128, scratch-bound).
// ---------------------------------------------------------------------------
__device__ inline void wg_barrier() {
    asm volatile("s_waitcnt lgkmcnt(0)" ::: "memory");
    __builtin_amdgcn_s_barrier();
    asm volatile("" ::: "memory");
}

#define LOADSET(GP, BASE, TT)                                                 \
    do {                                                                      \
        const _Float16* rp = (BASE) + (ptrdiff_t)(TT) * 8192;                 \
        GP##0 = *(const f16x4*)(rp);                                          \
        GP##1 = *(const f16x4*)(rp + 2048);                                   \
        GP##2 = *(const f16x4*)(rp + 4096);                                   \
        GP##3 = *(const f16x4*)(rp + 6144);                                   \
    } while (0)

#define ACTIVATE(CST, reg, ACC0, ACC1, ACC2, ACC3, HPK)                       \
    do {                                                                      \
        float i_ = ACC0, f_ = ACC1, g_ = ACC2, o_ = ACC3;                     \
        float Ei = __expf(-i_), Ef = __expf(-f_);                             \
        float Eg = __expf(-2.f * g_), Eo = __expf(-o_);                       \
        float a1 = 1.f + Ei, a2 = 1.f + Eg, a3 = 1.f + Ef;                    \
        float a12 = a1 * a2;                                                  \
        float num = CST[reg] * a12 + (1.f - Eg) * a3;                         \
        float cn = num * __builtin_amdgcn_rcpf(a3 * a12);                     \
        CST[reg] = cn;                                                        \
        float cc = fminf(fmaxf(cn, -15.f), 15.f);                             \
        float Ec = __expf(-2.f * cc);                                         \
        float hn = (1.f - Ec) *                                               \
            __builtin_amdgcn_rcpf((1.f + Eo) * (1.f + Ec));                   \
        HPK[reg] = (_Float16)hn;                                              \
    } while (0)

// One direction's step within a superstep. HB: this dir's hbuf. parity PH.
#define HALF_STEP(PH, GP, BASE, TT, TTPF, BFR, CST, HB, HROW, TGUARD)         \
    do {                                                                      \
        f16x8 afr[4];                                                         \
        {                                                                     \
            const unsigned sw2 = (unsigned)((l15 & 7) << 4);                  \
            _Pragma("unroll")                                                 \
            for (int kk = 0; kk < 4; ++kk) {                                  \
                unsigned bo = ((unsigned)(l15 * 256 + kk * 64 + l4 * 16)) ^   \
                              sw2;                                            \
                afr[kk] = *(const f16x8*)((const char*)HB[(PH) ^ 1] + bo);    \
            }                                                                 \
        }                                                                     \
        f32x4 acc[4];                                                         \
        _Pragma("unroll")                                                     \
        for (int reg = 0; reg < 4; ++reg) {                                   \
            acc[0][reg] = (float)GP##0[reg];                                  \
            acc[1][reg] = (float)GP##1[reg];                                  \
            acc[2][reg] = (float)GP##2[reg];                                  \
            acc[3][reg] = (float)GP##3[reg];                                  \
        }                                                                     \
        LOADSET(GP, BASE, TTPF);                                              \
        _Pragma("unroll")                                                     \
        for (int kk = 0; kk < 4; ++kk)                                        \
            _Pragma("unroll")                                                 \
            for (int q = 0; q < 4; ++q)                                       \
                acc[q] = __builtin_amdgcn_mfma_f32_16x16x32_f16(              \
                    afr[kk], BFR[q][kk], acc[q], 0, 0, 0);                    \
        f16x4 hpk;                                                            \
        _Pragma("unroll")                                                     \
        for (int reg = 0; reg < 4; ++reg) {                                   \
            ACTIVATE(CST, reg, acc[0][reg], acc[1][reg], acc[2][reg],         \
                     acc[3][reg], hpk);                                       \
            int rr = l4 * 4 + reg;                                            \
            unsigned bo = ((unsigned)(rr * 256 + u * 2)) ^                    \
                          (unsigned)((rr & 7) << 4);                          \
            *(_Float16*)((char*)HB[PH] + bo) = hpk[reg];                      \
        }                                                                     \
        if (TGUARD) {  /* wg-uniform scalar branch */                         \
            *(f16x4*)(HROW + (ptrdiff_t)(TT) * 8192) = hpk;                   \
        }                                                                     \
    } while (0)

#define SUPERSTEP(PH, GF, GB)                                                 \
    do {                                                                      \
        const int tF = s + (PH);                                              \
        const int tB = smax - 1 - (s + (PH));                                 \
        HALF_STEP(PH, GF, glaneF, tF, tF + 2, bfrF, cstF, hbufF, hrowF,       \
                  (tF < smax));                                               \
        HALF_STEP(PH, GB, glaneB, tB, tB - 2, bfrB, cstB, hbufB, hrowB,       \
                  (tB >= 0));                                                 \
        wg_barrier();                                                         \
    } while (0)

__global__ WAVES_EU_2 __launch_bounds__(512) void lstm_kernel(
    const _Float16* gi, _Float16* hws, const int* __restrict__ lengths,
    const float* __restrict__ Whh_f, const float* __restrict__ Whh_b)
{
    const int g   = blockIdx.x;          // 0..7
    const int tid = threadIdx.x;
    const int w   = tid >> 6;
    const int l   = tid & 63;
    const int l15 = l & 15, l4 = l >> 4;

    __shared__ __align__(16) _Float16 hbufF[2][kNB * kH];
    __shared__ __align__(16) _Float16 hbufB[2][kNB * kH];

    // ---- Whh B-fragments for BOTH dirs, resident in VGPRs ----
    f16x8 bfrF[4][4], bfrB[4][4];
    #pragma unroll
    for (int q = 0; q < 4; ++q) {
        #pragma unroll
        for (int kk = 0; kk < 4; ++kk) {
            int n  = q * 128 + w * 16 + l15;
            int k0 = kk * 32 + l4 * 8;
            const float* srcF = Whh_f + (size_t)n * kH + k0;
            const float* srcB = Whh_b + (size_t)n * kH + k0;
            float4 xf0 = *(const float4*)(srcF);
            float4 xf1 = *(const float4*)(srcF + 4);
            float4 xb0 = *(const float4*)(srcB);
            float4 xb1 = *(const float4*)(srcB + 4);
            f16x8 vf, vb;
            vf[0] = (_Float16)xf0.x; vf[1] = (_Float16)xf0.y;
            vf[2] = (_Float16)xf0.z; vf[3] = (_Float16)xf0.w;
            vf[4] = (_Float16)xf1.x; vf[5] = (_Float16)xf1.y;
            vf[6] = (_Float16)xf1.z; vf[7] = (_Float16)xf1.w;
            vb[0] = (_Float16)xb0.x; vb[1] = (_Float16)xb0.y;
            vb[2] = (_Float16)xb0.z; vb[3] = (_Float16)xb0.w;
            vb[4] = (_Float16)xb1.x; vb[5] = (_Float16)xb1.y;
            vb[6] = (_Float16)xb1.z; vb[7] = (_Float16)xb1.w;
            bfrF[q][kk] = vf;
            bfrB[q][kk] = vb;
        }
    }

    const int smax = lengths[g * kNB];
    const int smax_pad = (smax + 1) & ~1;

    const int u = w * 16 + l15;
    float cstF[4] = {0.f, 0.f, 0.f, 0.f};
    float cstB[4] = {0.f, 0.f, 0.f, 0.f};

    const _Float16* glaneF = gi + (size_t)g * kT * 8192
                                + (size_t)(u * 16 + l4 * 4);
    const _Float16* glaneB = gi + (size_t)(8 + g) * kT * 8192
                                + (size_t)(u * 16 + l4 * 4);
    _Float16* hrowF = hws + (size_t)g * kT * 8192 + (size_t)tid * 4;
    _Float16* hrowB = hws + (size_t)(8 + g) * kT * 8192 + (size_t)tid * 4;

    // zero-init hbuf parity-1 (read by first superstep) and prefetch 2-deep
    for (int i = tid; i < kNB * kH; i += 512) {
        hbufF[1][i] = (_Float16)0.f;
        hbufB[1][i] = (_Float16)0.f;
    }

    f16x4 gF00, gF01, gF02, gF03, gF10, gF11, gF12, gF13;
    f16x4 gB00, gB01, gB02, gB03, gB10, gB11, gB12, gB13;
    LOADSET(gF0, glaneF, 0);
    LOADSET(gF1, glaneF, 1);
    LOADSET(gB0, glaneB, smax - 1);
    LOADSET(gB1, glaneB, smax - 2);

    wg_barrier();   // hbuf zeros visible

    for (int s = 0; s < smax_pad; s += 2) {
        SUPERSTEP(0, gF0, gB0);
        SUPERSTEP(1, gF1, gB1);
    }
}

// ---------------------------------------------------------------------------
// Kernel 2b: feats. wg per (g, t): stage both dir h-rows (4KB each) + Wt,
// 144 threads compute fsum[b][t][k] = hf.Wt[:, :128] + hb.Wt[:, 128:] + bt.
// ---------------------------------------------------------------------------
__global__ __launch_bounds__(256) void feats_kernel(
    const _Float16* __restrict__ hws, const float* __restrict__ Wt,
    const float* __restrict__ bt, float* __restrict__ fsum)
{
    __shared__ _Float16 hf[2048], hb[2048];
    __shared__ float wts[kK * 256];
    __shared__ float bts[kK];
    const int g = blockIdx.x >> 9;
    const int t = blockIdx.x & 511;
    const int tid = threadIdx.x;

    *(f16x8*)&hf[tid * 8] =
        *(const f16x8*)(hws + ((size_t)g * kT + t) * 8192 + tid * 8);
    *(f16x8*)&hb[tid * 8] =
        *(const f16x8*)(hws + ((size_t)(8 + g) * kT + t) * 8192 + tid * 8);
    for (int i = tid; i < kK * 256; i += 256) wts[i] = Wt[i];
    if (tid < kK) bts[tid] = bt[tid];
    __syncthreads();

    if (tid < 144) {
        const int k = tid >> 4;      // 0..8
        const int r = tid & 15;      // chain in group
        float acc = bts[k];
        #pragma unroll 8
        for (int uu = 0; uu < kH; ++uu) {
            int idx = (uu >> 4) * 256 + (r >> 2) * 64 + (uu & 15) * 4 + (r & 3);
            acc += (float)hf[idx] * wts[k * 256 + uu] +
                   (float)hb[idx] * wts[k * 256 + 128 + uu];
        }
        fsum[((size_t)(g * 16 + r) * kT + t) * kK + k] = acc;
    }
}

// ---------------------------------------------------------------------------
// Kernel 3: CRF Viterbi via max-plus matrix reduction tree.
// ---------------------------------------------------------------------------
__global__ __launch_bounds__(512) void viterbi_kernel(
    const int* __restrict__ lengths, const float* __restrict__ trans,
    const float* __restrict__ fsumg, float* __restrict__ out)
{
    constexpr float NEG = -1e30f;
    constexpr int RA = 0;
    constexpr int RB = 128 * 81;
    const int b = blockIdx.x;
    const int len = lengths[b];
    const int tid = threadIdx.x;

    __shared__ float tree[(128 + 64) * 81];
    __shared__ float fsum[kT * kK];
    __shared__ float trs[81];
    __shared__ float red[16];

    if (tid < 81) trs[tid] = trans[tid];
    for (int idx = tid; idx < len * kK; idx += 512)
        fsum[idx] = fsumg[(size_t)b * kT * kK + idx];
    __syncthreads();

    for (int task = tid; task < 128 * 9; task += 512) {
        int s = task / 9, j = task - s * 9;
        int tb = 4 * s;
        float uu[9];
        #pragma unroll
        for (int m = 0; m < 9; ++m)
            uu[m] = (tb < len) ? (trs[m * 9 + j] + fsum[tb * 9 + m])
                               : ((m == j) ? 0.f : NEG);
        #pragma unroll
        for (int q = 1; q < 4; ++q) {
            int t = tb + q;
            if (t < len) {
                float un[9];
                #pragma unroll
                for (int k = 0; k < 9; ++k) {
                    float v = trs[k * 9] + uu[0];
                    #pragma unroll
                    for (int m = 1; m < 9; ++m)
                        v = fmaxf(v, trs[k * 9 + m] + uu[m]);
                    un[k] = v + fsum[t * 9 + k];
                }
                #pragma unroll
                for (int k = 0; k < 9; ++k) uu[k] = un[k];
            }
        }
        #pragma unroll
        for (int k = 0; k < 9; ++k)
            tree[RA + s * 81 + k * 9 + j] = uu[k];
    }
    __syncthreads();

    int soff = RA, doff = RB;
    for (int np = 64; np >= 1; np >>= 1) {
        for (int idx = tid; idx < np * 81; idx += 512) {
            int s = idx / 81, o = idx - s * 81;
            int k = o / 9, j = o - k * 9;
            const float* A  = tree + soff + (2 * s + 1) * 81;
            const float* Bm = tree + soff + (2 * s) * 81;
            float v = A[k * 9] + Bm[j];
            #pragma unroll
            for (int m = 1; m < 9; ++m)
                v = fmaxf(v, A[k * 9 + m] + Bm[m * 9 + j]);
            tree[doff + s * 81 + o] = v;
        }
        int tmp = soff; soff = doff; doff = tmp;
        __syncthreads();
    }
    if (tid < kK) {
        int k = tid;
        float fv = tree[soff + k * 9 + kSTART];
        #pragma unroll
        for (int j = 0; j < 9; ++j)
            if (j != kSTART) fv = fmaxf(fv, tree[soff + k * 9 + j] - 10000.f);
        red[k] = fv + trs[kSTOP * 9 + k];
    }
    __syncthreads();
    if (tid == 0) {
        float m = red[0];
        #pragma unroll
        for (int k = 1; k < 9; ++k) m = fmaxf(m, red[k]);
        out[b] = m;
    }
}

// ---------------------------------------------------------------------------
extern "C" void kernel_launch(void* const* d_in, const int* in_sizes, int n_in,
                              void* d_out, int out_size, void* d_ws, size_t ws_size,
                              hipStream_t stream) {
    const int*   sentence = (const int*)d_in[0];
    const int*   lengths  = (const int*)d_in[1];
    const float* emb      = (const float*)d_in[2];
    const float* Wih_f    = (const float*)d_in[3];
    const float* Whh_f    = (const float*)d_in[4];
    const float* b_f      = (const float*)d_in[5];
    const float* Wih_b    = (const float*)d_in[6];
    const float* Whh_b    = (const float*)d_in[7];
    const float* b_b      = (const float*)d_in[8];
    const float* Wt       = (const float*)d_in[9];
    const float* bt       = (const float*)d_in[10];
    const float* trans    = (const float*)d_in[11];
    float* out = (float*)d_out;

    char* ws = (char*)d_ws;
    const size_t gi_bytes = (size_t)2 * kB * kT * kG * sizeof(_Float16); // 128 MiB
    _Float16* gi   = (_Float16*)ws;
    _Float16* hws  = (_Float16*)ws;                  // aliases gi row heads
    float*    fsum = (float*)(ws + gi_bytes);        // 2.25 MiB

    proj_kernel<<<512, 256, 0, stream>>>(sentence, lengths, emb,
                                         Wih_f, b_f, Wih_b, b_b, gi);
    lstm_kernel<<<8, 512, 0, stream>>>(gi, hws, lengths, Whh_f, Whh_b);
    feats_kernel<<<4096, 256, 0, stream>>>(hws, Wt, bt, fsum);
    viterbi_kernel<<<128, 512, 0, stream>>>(lengths, trans, fsum, out);
}

// Round 13
// 710.816 us; speedup vs baseline: 1.4526x; 1.4526x over previous
//
#include <hip/hip_runtime.h>

typedef float f32x4 __attribute__((ext_vector_type(4)));
typedef _Float16 f16x8 __attribute__((ext_vector_type(8)));
typedef _Float16 f16x4 __attribute__((ext_vector_type(4)));

constexpr int kB = 128;     // batch
constexpr int kT = 512;     // time
constexpr int kD = 256;     // emb dim
constexpr int kG = 512;     // 4*H gates per direction
constexpr int kH = 128;     // hidden
constexpr int kK = 9;       // CRF states
constexpr int kSTART = 7;
constexpr int kSTOP = 8;
constexpr int kNB = 16;     // chains per LSTM workgroup

// gi layout, f16:  [dirg = dir*8+g][t][q(4)][u(128)][r(16)]; row = 8192 f16.
// proj ZERO-FILLS gi for t >= len[chain] -> lstm needs no length masking.
// hws (h output) aliases gi row head [0,2048): stores trail consumption.
// Prefetch overruns (fwd up, bwd down, +-4 rows) stay inside the gi region.

// ---------------------------------------------------------------------------
// Kernel 1: embedding gather + input projection (f16 MFMA GEMM).
// v2: W is NOT staged in LDS -- B-fragments loaded per-lane from global
// (weights are 2MB, L2/L3-resident) and converted in-register. LDS = A only
// (64.5KB) -> 2 wgs/CU, and ZERO barriers after the single A-stage sync.
// ---------------------------------------------------------------------------
__global__ __launch_bounds__(256) void proj_kernel(
    const int* __restrict__ sentence, const int* __restrict__ lengths,
    const float* __restrict__ emb,
    const float* __restrict__ Wih_f, const float* __restrict__ b_f,
    const float* __restrict__ Wih_b, const float* __restrict__ b_b,
    _Float16* __restrict__ gi)
{
    __shared__ __align__(16) _Float16 smemA[128 * 256]; // rows=(t,chain), 512B

    const int g  = blockIdx.x >> 6;
    const int tc = blockIdx.x & 63;
    if (tc * 8 >= lengths[g * 16]) return;   // whole 8-t chunk beyond group max
    const int tid = threadIdx.x;

    // ---- stage A once: row = t_local*16 + chain ----
    {
        const int row = tid >> 1;
        const int kb  = (tid & 1) << 7;
        const int b   = g * 16 + (row & 15);
        const int t   = tc * 8 + (row >> 4);
        const int vocab = sentence[b * kT + t];
        const float* src = emb + (size_t)vocab * kD + kb;
        const unsigned rowbyte = row * 512;
        const unsigned sw = (row & 7) << 4;
        #pragma unroll
        for (int c = 0; c < 16; ++c) {
            float4 x0 = *(const float4*)(src + c * 8);
            float4 x1 = *(const float4*)(src + c * 8 + 4);
            f16x8 pk;
            pk[0] = (_Float16)x0.x; pk[1] = (_Float16)x0.y;
            pk[2] = (_Float16)x0.z; pk[3] = (_Float16)x0.w;
            pk[4] = (_Float16)x1.x; pk[5] = (_Float16)x1.y;
            pk[6] = (_Float16)x1.z; pk[7] = (_Float16)x1.w;
            unsigned byteoff = rowbyte + ((unsigned)((kb + c * 8) * 2) ^ sw);
            *(f16x8*)((char*)smemA + byteoff) = pk;
        }
    }

    const int w    = tid >> 6;
    const int lane = tid & 63;
    const int wr = w >> 1, wc = w & 1;
    const int l15 = lane & 15, l4 = lane >> 4;

    int lene[4];
    #pragma unroll
    for (int rg = 0; rg < 4; ++rg)
        lene[rg] = lengths[g * 16 + l4 * 4 + rg];

    __syncthreads();   // A staged; the ONLY barrier in this kernel

    for (int by = 0; by < 8; ++by) {
        const int dir = by >> 2;
        const int q   = by & 3;
        const float* Wp = (dir == 0) ? Wih_f : Wih_b;

        f32x4 zero = {0.f, 0.f, 0.f, 0.f};
        f32x4 acc[4][4];
        #pragma unroll
        for (int mf = 0; mf < 4; ++mf)
            #pragma unroll
            for (int nf = 0; nf < 4; ++nf) acc[mf][nf] = zero;

        #pragma unroll
        for (int kk = 0; kk < 8; ++kk) {
            f16x8 afr[4], bfr[4];
            #pragma unroll
            for (int mf = 0; mf < 4; ++mf) {
                int row = wr * 64 + mf * 16 + l15;
                unsigned byteoff = row * 512 +
                    ((unsigned)(kk * 64 + l4 * 16) ^ (unsigned)((row & 7) << 4));
                afr[mf] = *(const f16x8*)((const char*)smemA + byteoff);
            }
            #pragma unroll
            for (int nf = 0; nf < 4; ++nf) {
                int n = q * 128 + wc * 64 + nf * 16 + l15;   // gate row
                const float* src = Wp + (size_t)n * kD + kk * 32 + l4 * 8;
                float4 x0 = *(const float4*)(src);
                float4 x1 = *(const float4*)(src + 4);
                f16x8 v;
                v[0] = (_Float16)x0.x; v[1] = (_Float16)x0.y;
                v[2] = (_Float16)x0.z; v[3] = (_Float16)x0.w;
                v[4] = (_Float16)x1.x; v[5] = (_Float16)x1.y;
                v[6] = (_Float16)x1.z; v[7] = (_Float16)x1.w;
                bfr[nf] = v;
            }
            #pragma unroll
            for (int mf = 0; mf < 4; ++mf)
                #pragma unroll
                for (int nf = 0; nf < 4; ++nf)
                    acc[mf][nf] = __builtin_amdgcn_mfma_f32_16x16x32_f16(
                        afr[mf], bfr[nf], acc[mf][nf], 0, 0, 0);
        }

        // ---- epilogue: one f16x4 (8B) store per fragment; zero for t>=len ---
        const float* biasp = (dir == 0) ? b_f : b_b;
        _Float16* dbase = gi + (size_t)(dir * 8 + g) * kT * 8192;
        #pragma unroll
        for (int nf = 0; nf < 4; ++nf) {
            int u = wc * 64 + nf * 16 + l15;
            float bias = biasp[q * 128 + u];
            #pragma unroll
            for (int mf = 0; mf < 4; ++mf) {
                int t = tc * 8 + wr * 4 + mf;
                f16x4 pk;
                #pragma unroll
                for (int rg = 0; rg < 4; ++rg) {
                    float v = (t < lene[rg]) ? (acc[mf][nf][rg] + bias) : 0.f;
                    pk[rg] = (_Float16)v;
                }
                *(f16x4*)(dbase + (size_t)t * 8192 + (q * 128 + u) * 16 + l4 * 4) = pk;
            }
        }
    }
}

// ---------------------------------------------------------------------------
// Kernel 2: persistent weight-stationary LSTM. 16 wgs x 512 thr.  [R9 exact]
// 4-phase unroll, 4-deep prefetch, counted lgkm barrier, merged-rcp
// activation, no length masks (gi zero-filled), padded loop + uniform guard.
// ---------------------------------------------------------------------------
__device__ inline void wg_barrier() {
    asm volatile("s_waitcnt lgkmcnt(0)" ::: "memory");
    __builtin_amdgcn_s_barrier();
    asm volatile("" ::: "memory");
}

#define LOADSET(GP, SS)                                                       \
    do {                                                                      \
        int tt = dir ? (smax - 1 - (SS)) : (SS);                              \
        const _Float16* rp = glane + (ptrdiff_t)tt * 8192;                    \
        GP##0 = *(const f16x4*)(rp);                                          \
        GP##1 = *(const f16x4*)(rp + 2048);                                   \
        GP##2 = *(const f16x4*)(rp + 4096);                                   \
        GP##3 = *(const f16x4*)(rp + 6144);                                   \
    } while (0)

#define ACTIVATE(reg, ACC0, ACC1, ACC2, ACC3, HPK)                            \
    do {                                                                      \
        float i_ = ACC0, f_ = ACC1, g_ = ACC2, o_ = ACC3;                     \
        float Ei = __expf(-i_), Ef = __expf(-f_);                             \
        float Eg = __expf(-2.f * g_), Eo = __expf(-o_);                       \
        float a1 = 1.f + Ei, a2 = 1.f + Eg, a3 = 1.f + Ef;                    \
        float a12 = a1 * a2;                                                  \
        float num = cst[reg] * a12 + (1.f - Eg) * a3;                         \
        float cn = num * __builtin_amdgcn_rcpf(a3 * a12);                     \
        cst[reg] = cn;                                                        \
        float cc = fminf(fmaxf(cn, -15.f), 15.f);                             \
        float Ec = __expf(-2.f * cc);                                         \
        float hn = (1.f - Ec) *                                               \
            __builtin_amdgcn_rcpf((1.f + Eo) * (1.f + Ec));                   \
        HPK[reg] = (_Float16)hn;                                              \
    } while (0)

#define LSTM_BODY(PH, GP)                                                     \
    do {                                                                      \
        const int tb = dir ? (smax - 1 - (s + PH)) : (s + PH);                \
        f32x4 acc[4];                                                         \
        _Pragma("unroll")                                                     \
        for (int reg = 0; reg < 4; ++reg) {                                   \
            acc[0][reg] = (float)GP##0[reg];                                  \
            acc[1][reg] = (float)GP##1[reg];                                  \
            acc[2][reg] = (float)GP##2[reg];                                  \
            acc[3][reg] = (float)GP##3[reg];                                  \
        }                                                                     \
        LOADSET(GP, s + PH + 4);                                              \
        _Pragma("unroll")                                                     \
        for (int kk = 0; kk < 4; ++kk)                                        \
            _Pragma("unroll")                                                 \
            for (int q = 0; q < 4; ++q)                                       \
                acc[q] = __builtin_amdgcn_mfma_f32_16x16x32_f16(              \
                    afr[kk], bfr[q][kk], acc[q], 0, 0, 0);                    \
        f16x4 hpk;                                                            \
        _Pragma("unroll")                                                     \
        for (int reg = 0; reg < 4; ++reg) {                                   \
            ACTIVATE(reg, acc[0][reg], acc[1][reg], acc[2][reg],              \
                     acc[3][reg], hpk);                                       \
            int rr = l4 * 4 + reg;                                            \
            unsigned bo = ((unsigned)(rr * 256 + u * 2)) ^                    \
                          (unsigned)((rr & 7) << 4);                          \
            *(_Float16*)((char*)hbuf[(PH) & 1] + bo) = hpk[reg];              \
        }                                                                     \
        if ((unsigned)tb < (unsigned)smax) {  /* wg-uniform scalar branch */  \
            *(f16x4*)(hrow_base + (size_t)tb * 8192) = hpk;                   \
        }                                                                     \
        wg_barrier();                                                         \
        {                                                                     \
            const unsigned sw2 = (unsigned)((l15 & 7) << 4);                  \
            _Pragma("unroll")                                                 \
            for (int kk = 0; kk < 4; ++kk) {                                  \
                unsigned bo = ((unsigned)(l15 * 256 + kk * 64 + l4 * 16)) ^   \
                              sw2;                                            \
                afr[kk] = *(const f16x8*)((const char*)hbuf[(PH) & 1] + bo);  \
            }                                                                 \
        }                                                                     \
    } while (0)

__global__ __launch_bounds__(512) void lstm_kernel(
    const _Float16* gi, _Float16* hws, const int* __restrict__ lengths,
    const float* __restrict__ Whh_f, const float* __restrict__ Whh_b)
{
    const int bid = blockIdx.x;          // 0..15
    const int dir = bid >> 3;
    const int g   = bid & 7;
    const int tid = threadIdx.x;
    const int w   = tid >> 6;
    const int l   = tid & 63;
    const int l15 = l & 15, l4 = l >> 4;

    __shared__ __align__(16) _Float16 hbuf[2][kNB * kH];

    // ---- Whh B-fragments resident in VGPRs ----
    const float* Whh = dir ? Whh_b : Whh_f;
    f16x8 bfr[4][4];
    #pragma unroll
    for (int q = 0; q < 4; ++q) {
        #pragma unroll
        for (int kk = 0; kk < 4; ++kk) {
            int n  = q * 128 + w * 16 + l15;
            int k0 = kk * 32 + l4 * 8;
            const float* src = Whh + (size_t)n * kH + k0;
            float4 x0 = *(const float4*)(src);
            float4 x1 = *(const float4*)(src + 4);
            f16x8 v;
            v[0] = (_Float16)x0.x; v[1] = (_Float16)x0.y;
            v[2] = (_Float16)x0.z; v[3] = (_Float16)x0.w;
            v[4] = (_Float16)x1.x; v[5] = (_Float16)x1.y;
            v[6] = (_Float16)x1.z; v[7] = (_Float16)x1.w;
            bfr[q][kk] = v;
        }
    }

    const int smax = lengths[g * kNB];
    const int smax_pad = (smax + 3) & ~3;

    const int u = w * 16 + l15;
    float cst[4] = {0.f, 0.f, 0.f, 0.f};
    f16x8 afr[4];
    #pragma unroll
    for (int kk = 0; kk < 4; ++kk)
        #pragma unroll
        for (int j = 0; j < 8; ++j) afr[kk][j] = (_Float16)0.f;

    const _Float16* glane = gi + (size_t)(dir * 8 + g) * kT * 8192
                               + (size_t)(u * 16 + l4 * 4);
    _Float16* hrow_base = hws + (size_t)(dir * 8 + g) * kT * 8192
                              + (size_t)tid * 4;

    f16x4 gA0, gA1, gA2, gA3, gB0, gB1, gB2, gB3;
    f16x4 gC0, gC1, gC2, gC3, gD0, gD1, gD2, gD3;
    LOADSET(gA, 0); LOADSET(gB, 1); LOADSET(gC, 2); LOADSET(gD, 3);

    for (int s = 0; s < smax_pad; s += 4) {
        LSTM_BODY(0, gA);
        LSTM_BODY(1, gB);
        LSTM_BODY(2, gC);
        LSTM_BODY(3, gD);
    }
}

// ---------------------------------------------------------------------------
// Kernel 2b: feats. wg per (g, 4 t's): stage 4x both-dir h-rows (32KB) + Wt
// once, 576 tasks over 256 threads. Grid 1024 (was 4096): Wt staging /4.
// ---------------------------------------------------------------------------
__global__ __launch_bounds__(256) void feats_kernel(
    const _Float16* __restrict__ hws, const float* __restrict__ Wt,
    const float* __restrict__ bt, float* __restrict__ fsum)
{
    __shared__ _Float16 hf[4][2048], hb[4][2048];
    __shared__ float wts[kK * 256];
    __shared__ float bts[kK];
    const int g  = blockIdx.x >> 7;      // 0..7
    const int t0 = (blockIdx.x & 127) * 4;
    const int tid = threadIdx.x;

    #pragma unroll
    for (int j = 0; j < 4; ++j) {
        *(f16x8*)&hf[j][tid * 8] =
            *(const f16x8*)(hws + ((size_t)g * kT + t0 + j) * 8192 + tid * 8);
        *(f16x8*)&hb[j][tid * 8] =
            *(const f16x8*)(hws + ((size_t)(8 + g) * kT + t0 + j) * 8192 + tid * 8);
    }
    for (int i = tid; i < kK * 256; i += 256) wts[i] = Wt[i];
    if (tid < kK) bts[tid] = bt[tid];
    __syncthreads();

    for (int task = tid; task < 4 * 144; task += 256) {
        const int tl  = task / 144;
        const int rem = task - tl * 144;
        const int k = rem >> 4;      // 0..8
        const int r = rem & 15;      // chain in group
        float acc = bts[k];
        #pragma unroll 8
        for (int uu = 0; uu < kH; ++uu) {
            int idx = (uu >> 4) * 256 + (r >> 2) * 64 + (uu & 15) * 4 + (r & 3);
            acc += (float)hf[tl][idx] * wts[k * 256 + uu] +
                   (float)hb[tl][idx] * wts[k * 256 + 128 + uu];
        }
        fsum[((size_t)(g * 16 + r) * kT + t0 + tl) * kK + k] = acc;
    }
}

// ---------------------------------------------------------------------------
// Kernel 3: CRF Viterbi via max-plus matrix reduction tree.  [unchanged]
// ---------------------------------------------------------------------------
__global__ __launch_bounds__(512) void viterbi_kernel(
    const int* __restrict__ lengths, const float* __restrict__ trans,
    const float* __restrict__ fsumg, float* __restrict__ out)
{
    constexpr float NEG = -1e30f;
    constexpr int RA = 0;
    constexpr int RB = 128 * 81;
    const int b = blockIdx.x;
    const int len = lengths[b];
    const int tid = threadIdx.x;

    __shared__ float tree[(128 + 64) * 81];
    __shared__ float fsum[kT * kK];
    __shared__ float trs[81];
    __shared__ float red[16];

    if (tid < 81) trs[tid] = trans[tid];
    for (int idx = tid; idx < len * kK; idx += 512)
        fsum[idx] = fsumg[(size_t)b * kT * kK + idx];
    __syncthreads();

    for (int task = tid; task < 128 * 9; task += 512) {
        int s = task / 9, j = task - s * 9;
        int tb = 4 * s;
        float uu[9];
        #pragma unroll
        for (int m = 0; m < 9; ++m)
            uu[m] = (tb < len) ? (trs[m * 9 + j] + fsum[tb * 9 + m])
                               : ((m == j) ? 0.f : NEG);
        #pragma unroll
        for (int q = 1; q < 4; ++q) {
            int t = tb + q;
            if (t < len) {
                float un[9];
                #pragma unroll
                for (int k = 0; k < 9; ++k) {
                    float v = trs[k * 9] + uu[0];
                    #pragma unroll
                    for (int m = 1; m < 9; ++m)
                        v = fmaxf(v, trs[k * 9 + m] + uu[m]);
                    un[k] = v + fsum[t * 9 + k];
                }
                #pragma unroll
                for (int k = 0; k < 9; ++k) uu[k] = un[k];
            }
        }
        #pragma unroll
        for (int k = 0; k < 9; ++k)
            tree[RA + s * 81 + k * 9 + j] = uu[k];
    }
    __syncthreads();

    int soff = RA, doff = RB;
    for (int np = 64; np >= 1; np >>= 1) {
        for (int idx = tid; idx < np * 81; idx += 512) {
            int s = idx / 81, o = idx - s * 81;
            int k = o / 9, j = o - k * 9;
            const float* A  = tree + soff + (2 * s + 1) * 81;
            const float* Bm = tree + soff + (2 * s) * 81;
            float v = A[k * 9] + Bm[j];
            #pragma unroll
            for (int m = 1; m < 9; ++m)
                v = fmaxf(v, A[k * 9 + m] + Bm[m * 9 + j]);
            tree[doff + s * 81 + o] = v;
        }
        int tmp = soff; soff = doff; doff = tmp;
        __syncthreads();
    }
    if (tid < kK) {
        int k = tid;
        float fv = tree[soff + k * 9 + kSTART];
        #pragma unroll
        for (int j = 0; j < 9; ++j)
            if (j != kSTART) fv = fmaxf(fv, tree[soff + k * 9 + j] - 10000.f);
        red[k] = fv + trs[kSTOP * 9 + k];
    }
    __syncthreads();
    if (tid == 0) {
        float m = red[0];
        #pragma unroll
        for (int k = 1; k < 9; ++k) m = fmaxf(m, red[k]);
        out[b] = m;
    }
}

// ---------------------------------------------------------------------------
extern "C" void kernel_launch(void* const* d_in, const int* in_sizes, int n_in,
                              void* d_out, int out_size, void* d_ws, size_t ws_size,
                              hipStream_t stream) {
    const int*   sentence = (const int*)d_in[0];
    const int*   lengths  = (const int*)d_in[1];
    const float* emb      = (const float*)d_in[2];
    const float* Wih_f    = (const float*)d_in[3];
    const float* Whh_f    = (const float*)d_in[4];
    const float* b_f      = (const float*)d_in[5];
    const float* Wih_b    = (const float*)d_in[6];
    const float* Whh_b    = (const float*)d_in[7];
    const float* b_b      = (const float*)d_in[8];
    const float* Wt       = (const float*)d_in[9];
    const float* bt       = (const float*)d_in[10];
    const float* trans    = (const float*)d_in[11];
    float* out = (float*)d_out;

    char* ws = (char*)d_ws;
    const size_t gi_bytes = (size_t)2 * kB * kT * kG * sizeof(_Float16); // 128 MiB
    _Float16* gi   = (_Float16*)ws;
    _Float16* hws  = (_Float16*)ws;                  // aliases gi row heads
    float*    fsum = (float*)(ws + gi_bytes);        // 2.25 MiB

    proj_kernel<<<512, 256, 0, stream>>>(sentence, lengths, emb,
                                         Wih_f, b_f, Wih_b, b_b, gi);
    lstm_kernel<<<16, 512, 0, stream>>>(gi, hws, lengths, Whh_f, Whh_b);
    feats_kernel<<<1024, 256, 0, stream>>>(hws, Wt, bt, fsum);
    viterbi_kernel<<<128, 512, 0, stream>>>(lengths, trans, fsum, out);
}

// Round 14
// 616.220 us; speedup vs baseline: 1.6756x; 1.1535x over previous
//
#include <hip/hip_runtime.h>

typedef float f32x4 __attribute__((ext_vector_type(4)));
typedef _Float16 f16x8 __attribute__((ext_vector_type(8)));
typedef _Float16 f16x4 __attribute__((ext_vector_type(4)));

constexpr int kB = 128;     // batch
constexpr int kT = 512;     // time
constexpr int kD = 256;     // emb dim
constexpr int kG = 512;     // 4*H gates per direction
constexpr int kH = 128;     // hidden
constexpr int kK = 9;       // CRF states
constexpr int kSTART = 7;
constexpr int kSTOP = 8;
constexpr int kNB = 16;     // chains per LSTM workgroup

// gi layout, f16:  [dirg = dir*8+g][t][q(4)][u(128)][r(16)]; row = 8192 f16.
// proj ZERO-FILLS gi for t >= len[chain] -> lstm needs no length masking.
// hws (h output) aliases gi row head [0,2048): stores trail consumption.
// Prefetch overruns (fwd up, bwd down, +-4 rows) stay inside the gi region.

// lgkm-only barrier: does NOT drain vmcnt, so global stores/loads in flight
// stay in flight across it (m97: __syncthreads emits vmcnt(0) drain).
__device__ inline void wg_barrier() {
    asm volatile("s_waitcnt lgkmcnt(0)" ::: "memory");
    __builtin_amdgcn_s_barrier();
    asm volatile("" ::: "memory");
}

// ---------------------------------------------------------------------------
// Kernel 1: embedding gather + input projection (f16 MFMA GEMM).
// R9 structure (A + W staged in LDS), with lgkm-only barriers: the 64
// epilogue gi-stores per by-iteration no longer drain before W re-staging
// (their only hazard is kernel-end, which the dispatch boundary covers).
// ---------------------------------------------------------------------------
__global__ __launch_bounds__(256) void proj_kernel(
    const int* __restrict__ sentence, const int* __restrict__ lengths,
    const float* __restrict__ emb,
    const float* __restrict__ Wih_f, const float* __restrict__ b_f,
    const float* __restrict__ Wih_b, const float* __restrict__ b_b,
    _Float16* __restrict__ gi)
{
    __shared__ __align__(16) _Float16 smemA[128 * 256]; // rows=(t,chain), 512B
    __shared__ __align__(16) _Float16 smemW[128 * 256]; // rows=gate, 512B

    const int g  = blockIdx.x >> 6;
    const int tc = blockIdx.x & 63;
    if (tc * 8 >= lengths[g * 16]) return;   // whole 8-t chunk beyond group max
    const int tid = threadIdx.x;

    // ---- stage A once: row = t_local*16 + chain ----
    {
        const int row = tid >> 1;
        const int kb  = (tid & 1) << 7;
        const int b   = g * 16 + (row & 15);
        const int t   = tc * 8 + (row >> 4);
        const int vocab = sentence[b * kT + t];
        const float* src = emb + (size_t)vocab * kD + kb;
        const unsigned rowbyte = row * 512;
        const unsigned sw = (row & 7) << 4;
        #pragma unroll
        for (int c = 0; c < 16; ++c) {
            float4 x0 = *(const float4*)(src + c * 8);
            float4 x1 = *(const float4*)(src + c * 8 + 4);
            f16x8 pk;
            pk[0] = (_Float16)x0.x; pk[1] = (_Float16)x0.y;
            pk[2] = (_Float16)x0.z; pk[3] = (_Float16)x0.w;
            pk[4] = (_Float16)x1.x; pk[5] = (_Float16)x1.y;
            pk[6] = (_Float16)x1.z; pk[7] = (_Float16)x1.w;
            unsigned byteoff = rowbyte + ((unsigned)((kb + c * 8) * 2) ^ sw);
            *(f16x8*)((char*)smemA + byteoff) = pk;
        }
    }

    const int w    = tid >> 6;
    const int lane = tid & 63;
    const int wr = w >> 1, wc = w & 1;
    const int l15 = lane & 15, l4 = lane >> 4;

    int lene[4];
    #pragma unroll
    for (int rg = 0; rg < 4; ++rg)
        lene[rg] = lengths[g * 16 + l4 * 4 + rg];

    for (int by = 0; by < 8; ++by) {
        const int dir = by >> 2;
        const int q   = by & 3;
        wg_barrier();        // prev compute's LDS reads done (and A staged)
        // ---- stage W rows for this (dir,q) ----
        {
            const int row = tid >> 1;
            const int kb  = (tid & 1) << 7;
            const float* src = (dir == 0 ? Wih_f : Wih_b)
                               + (size_t)(q * 128 + row) * kD + kb;
            const unsigned rowbyte = row * 512;
            const unsigned sw = (row & 7) << 4;
            #pragma unroll
            for (int c = 0; c < 16; ++c) {
                float4 x0 = *(const float4*)(src + c * 8);
                float4 x1 = *(const float4*)(src + c * 8 + 4);
                f16x8 pk;
                pk[0] = (_Float16)x0.x; pk[1] = (_Float16)x0.y;
                pk[2] = (_Float16)x0.z; pk[3] = (_Float16)x0.w;
                pk[4] = (_Float16)x1.x; pk[5] = (_Float16)x1.y;
                pk[6] = (_Float16)x1.z; pk[7] = (_Float16)x1.w;
                unsigned byteoff = rowbyte + ((unsigned)((kb + c * 8) * 2) ^ sw);
                *(f16x8*)((char*)smemW + byteoff) = pk;
            }
        }
        wg_barrier();        // W ds_writes visible

        f32x4 zero = {0.f, 0.f, 0.f, 0.f};
        f32x4 acc[4][4];
        #pragma unroll
        for (int mf = 0; mf < 4; ++mf)
            #pragma unroll
            for (int nf = 0; nf < 4; ++nf) acc[mf][nf] = zero;

        #pragma unroll
        for (int kk = 0; kk < 8; ++kk) {
            f16x8 afr[4], bfr[4];
            #pragma unroll
            for (int mf = 0; mf < 4; ++mf) {
                int row = wr * 64 + mf * 16 + l15;
                unsigned byteoff = row * 512 +
                    ((unsigned)(kk * 64 + l4 * 16) ^ (unsigned)((row & 7) << 4));
                afr[mf] = *(const f16x8*)((const char*)smemA + byteoff);
            }
            #pragma unroll
            for (int nf = 0; nf < 4; ++nf) {
                int row = wc * 64 + nf * 16 + l15;
                unsigned byteoff = row * 512 +
                    ((unsigned)(kk * 64 + l4 * 16) ^ (unsigned)((row & 7) << 4));
                bfr[nf] = *(const f16x8*)((const char*)smemW + byteoff);
            }
            #pragma unroll
            for (int mf = 0; mf < 4; ++mf)
                #pragma unroll
                for (int nf = 0; nf < 4; ++nf)
                    acc[mf][nf] = __builtin_amdgcn_mfma_f32_16x16x32_f16(
                        afr[mf], bfr[nf], acc[mf][nf], 0, 0, 0);
        }

        // ---- epilogue: one f16x4 (8B) store per fragment; zero for t>=len ---
        const float* biasp = (dir == 0) ? b_f : b_b;
        _Float16* dbase = gi + (size_t)(dir * 8 + g) * kT * 8192;
        #pragma unroll
        for (int nf = 0; nf < 4; ++nf) {
            int u = wc * 64 + nf * 16 + l15;
            float bias = biasp[q * 128 + u];
            #pragma unroll
            for (int mf = 0; mf < 4; ++mf) {
                int t = tc * 8 + wr * 4 + mf;
                f16x4 pk;
                #pragma unroll
                for (int rg = 0; rg < 4; ++rg) {
                    float v = (t < lene[rg]) ? (acc[mf][nf][rg] + bias) : 0.f;
                    pk[rg] = (_Float16)v;
                }
                *(f16x4*)(dbase + (size_t)t * 8192 + (q * 128 + u) * 16 + l4 * 4) = pk;
            }
        }
    }
}

// ---------------------------------------------------------------------------
// Kernel 2: persistent weight-stationary LSTM. 16 wgs x 512 thr.  [R9 exact]
// ---------------------------------------------------------------------------
#define LOADSET(GP, SS)                                                       \
    do {                                                                      \
        int tt = dir ? (smax - 1 - (SS)) : (SS);                              \
        const _Float16* rp = glane + (ptrdiff_t)tt * 8192;                    \
        GP##0 = *(const f16x4*)(rp);                                          \
        GP##1 = *(const f16x4*)(rp + 2048);                                   \
        GP##2 = *(const f16x4*)(rp + 4096);                                   \
        GP##3 = *(const f16x4*)(rp + 6144);                                   \
    } while (0)

#define ACTIVATE(reg, ACC0, ACC1, ACC2, ACC3, HPK)                            \
    do {                                                                      \
        float i_ = ACC0, f_ = ACC1, g_ = ACC2, o_ = ACC3;                     \
        float Ei = __expf(-i_), Ef = __expf(-f_);                             \
        float Eg = __expf(-2.f * g_), Eo = __expf(-o_);                       \
        float a1 = 1.f + Ei, a2 = 1.f + Eg, a3 = 1.f + Ef;                    \
        float a12 = a1 * a2;                                                  \
        float num = cst[reg] * a12 + (1.f - Eg) * a3;                         \
        float cn = num * __builtin_amdgcn_rcpf(a3 * a12);                     \
        cst[reg] = cn;                                                        \
        float cc = fminf(fmaxf(cn, -15.f), 15.f);                             \
        float Ec = __expf(-2.f * cc);                                         \
        float hn = (1.f - Ec) *                                               \
            __builtin_amdgcn_rcpf((1.f + Eo) * (1.f + Ec));                   \
        HPK[reg] = (_Float16)hn;                                              \
    } while (0)

#define LSTM_BODY(PH, GP)                                                     \
    do {                                                                      \
        const int tb = dir ? (smax - 1 - (s + PH)) : (s + PH);                \
        f32x4 acc[4];                                                         \
        _Pragma("unroll")                                                     \
        for (int reg = 0; reg < 4; ++reg) {                                   \
            acc[0][reg] = (float)GP##0[reg];                                  \
            acc[1][reg] = (float)GP##1[reg];                                  \
            acc[2][reg] = (float)GP##2[reg];                                  \
            acc[3][reg] = (float)GP##3[reg];                                  \
        }                                                                     \
        LOADSET(GP, s + PH + 4);                                              \
        _Pragma("unroll")                                                     \
        for (int kk = 0; kk < 4; ++kk)                                        \
            _Pragma("unroll")                                                 \
            for (int q = 0; q < 4; ++q)                                       \
                acc[q] = __builtin_amdgcn_mfma_f32_16x16x32_f16(              \
                    afr[kk], bfr[q][kk], acc[q], 0, 0, 0);                    \
        f16x4 hpk;                                                            \
        _Pragma("unroll")                                                     \
        for (int reg = 0; reg < 4; ++reg) {                                   \
            ACTIVATE(reg, acc[0][reg], acc[1][reg], acc[2][reg],              \
                     acc[3][reg], hpk);                                       \
            int rr = l4 * 4 + reg;                                            \
            unsigned bo = ((unsigned)(rr * 256 + u * 2)) ^                    \
                          (unsigned)((rr & 7) << 4);                          \
            *(_Float16*)((char*)hbuf[(PH) & 1] + bo) = hpk[reg];              \
        }                                                                     \
        if ((unsigned)tb < (unsigned)smax) {  /* wg-uniform scalar branch */  \
            *(f16x4*)(hrow_base + (size_t)tb * 8192) = hpk;                   \
        }                                                                     \
        wg_barrier();                                                         \
        {                                                                     \
            const unsigned sw2 = (unsigned)((l15 & 7) << 4);                  \
            _Pragma("unroll")                                                 \
            for (int kk = 0; kk < 4; ++kk) {                                  \
                unsigned bo = ((unsigned)(l15 * 256 + kk * 64 + l4 * 16)) ^   \
                              sw2;                                            \
                afr[kk] = *(const f16x8*)((const char*)hbuf[(PH) & 1] + bo);  \
            }                                                                 \
        }                                                                     \
    } while (0)

__global__ __launch_bounds__(512) void lstm_kernel(
    const _Float16* gi, _Float16* hws, const int* __restrict__ lengths,
    const float* __restrict__ Whh_f, const float* __restrict__ Whh_b)
{
    const int bid = blockIdx.x;          // 0..15
    const int dir = bid >> 3;
    const int g   = bid & 7;
    const int tid = threadIdx.x;
    const int w   = tid >> 6;
    const int l   = tid & 63;
    const int l15 = l & 15, l4 = l >> 4;

    __shared__ __align__(16) _Float16 hbuf[2][kNB * kH];

    // ---- Whh B-fragments resident in VGPRs ----
    const float* Whh = dir ? Whh_b : Whh_f;
    f16x8 bfr[4][4];
    #pragma unroll
    for (int q = 0; q < 4; ++q) {
        #pragma unroll
        for (int kk = 0; kk < 4; ++kk) {
            int n  = q * 128 + w * 16 + l15;
            int k0 = kk * 32 + l4 * 8;
            const float* src = Whh + (size_t)n * kH + k0;
            float4 x0 = *(const float4*)(src);
            float4 x1 = *(const float4*)(src + 4);
            f16x8 v;
            v[0] = (_Float16)x0.x; v[1] = (_Float16)x0.y;
            v[2] = (_Float16)x0.z; v[3] = (_Float16)x0.w;
            v[4] = (_Float16)x1.x; v[5] = (_Float16)x1.y;
            v[6] = (_Float16)x1.z; v[7] = (_Float16)x1.w;
            bfr[q][kk] = v;
        }
    }

    const int smax = lengths[g * kNB];
    const int smax_pad = (smax + 3) & ~3;

    const int u = w * 16 + l15;
    float cst[4] = {0.f, 0.f, 0.f, 0.f};
    f16x8 afr[4];
    #pragma unroll
    for (int kk = 0; kk < 4; ++kk)
        #pragma unroll
        for (int j = 0; j < 8; ++j) afr[kk][j] = (_Float16)0.f;

    const _Float16* glane = gi + (size_t)(dir * 8 + g) * kT * 8192
                               + (size_t)(u * 16 + l4 * 4);
    _Float16* hrow_base = hws + (size_t)(dir * 8 + g) * kT * 8192
                              + (size_t)tid * 4;

    f16x4 gA0, gA1, gA2, gA3, gB0, gB1, gB2, gB3;
    f16x4 gC0, gC1, gC2, gC3, gD0, gD1, gD2, gD3;
    LOADSET(gA, 0); LOADSET(gB, 1); LOADSET(gC, 2); LOADSET(gD, 3);

    for (int s = 0; s < smax_pad; s += 4) {
        LSTM_BODY(0, gA);
        LSTM_BODY(1, gB);
        LSTM_BODY(2, gC);
        LSTM_BODY(3, gD);
    }
}

// ---------------------------------------------------------------------------
// Kernel 2b: feats. wg per (g, t): stage both dir h-rows (4KB each) + Wt,
// 144 threads compute fsum[b][t][k] = hf.Wt[:, :128] + hb.Wt[:, 128:] + bt.
// [R9 exact]
// ---------------------------------------------------------------------------
__global__ __launch_bounds__(256) void feats_kernel(
    const _Float16* __restrict__ hws, const float* __restrict__ Wt,
    const float* __restrict__ bt, float* __restrict__ fsum)
{
    __shared__ _Float16 hf[2048], hb[2048];
    __shared__ float wts[kK * 256];
    __shared__ float bts[kK];
    const int g = blockIdx.x >> 9;
    const int t = blockIdx.x & 511;
    const int tid = threadIdx.x;

    *(f16x8*)&hf[tid * 8] =
        *(const f16x8*)(hws + ((size_t)g * kT + t) * 8192 + tid * 8);
    *(f16x8*)&hb[tid * 8] =
        *(const f16x8*)(hws + ((size_t)(8 + g) * kT + t) * 8192 + tid * 8);
    for (int i = tid; i < kK * 256; i += 256) wts[i] = Wt[i];
    if (tid < kK) bts[tid] = bt[tid];
    __syncthreads();

    if (tid < 144) {
        const int k = tid >> 4;      // 0..8
        const int r = tid & 15;      // chain in group
        float acc = bts[k];
        #pragma unroll 8
        for (int uu = 0; uu < kH; ++uu) {
            int idx = (uu >> 4) * 256 + (r >> 2) * 64 + (uu & 15) * 4 + (r & 3);
            acc += (float)hf[idx] * wts[k * 256 + uu] +
                   (float)hb[idx] * wts[k * 256 + 128 + uu];
        }
        fsum[((size_t)(g * 16 + r) * kT + t) * kK + k] = acc;
    }
}

// ---------------------------------------------------------------------------
// Kernel 3: CRF Viterbi via max-plus matrix reduction tree.  [unchanged]
// ---------------------------------------------------------------------------
__global__ __launch_bounds__(512) void viterbi_kernel(
    const int* __restrict__ lengths, const float* __restrict__ trans,
    const float* __restrict__ fsumg, float* __restrict__ out)
{
    constexpr float NEG = -1e30f;
    constexpr int RA = 0;
    constexpr int RB = 128 * 81;
    const int b = blockIdx.x;
    const int len = lengths[b];
    const int tid = threadIdx.x;

    __shared__ float tree[(128 + 64) * 81];
    __shared__ float fsum[kT * kK];
    __shared__ float trs[81];
    __shared__ float red[16];

    if (tid < 81) trs[tid] = trans[tid];
    for (int idx = tid; idx < len * kK; idx += 512)
        fsum[idx] = fsumg[(size_t)b * kT * kK + idx];
    __syncthreads();

    for (int task = tid; task < 128 * 9; task += 512) {
        int s = task / 9, j = task - s * 9;
        int tb = 4 * s;
        float uu[9];
        #pragma unroll
        for (int m = 0; m < 9; ++m)
            uu[m] = (tb < len) ? (trs[m * 9 + j] + fsum[tb * 9 + m])
                               : ((m == j) ? 0.f : NEG);
        #pragma unroll
        for (int q = 1; q < 4; ++q) {
            int t = tb + q;
            if (t < len) {
                float un[9];
                #pragma unroll
                for (int k = 0; k < 9; ++k) {
                    float v = trs[k * 9] + uu[0];
                    #pragma unroll
                    for (int m = 1; m < 9; ++m)
                        v = fmaxf(v, trs[k * 9 + m] + uu[m]);
                    un[k] = v + fsum[t * 9 + k];
                }
                #pragma unroll
                for (int k = 0; k < 9; ++k) uu[k] = un[k];
            }
        }
        #pragma unroll
        for (int k = 0; k < 9; ++k)
            tree[RA + s * 81 + k * 9 + j] = uu[k];
    }
    __syncthreads();

    int soff = RA, doff = RB;
    for (int np = 64; np >= 1; np >>= 1) {
        for (int idx = tid; idx < np * 81; idx += 512) {
            int s = idx / 81, o = idx - s * 81;
            int k = o / 9, j = o - k * 9;
            const float* A  = tree + soff + (2 * s + 1) * 81;
            const float* Bm = tree + soff + (2 * s) * 81;
            float v = A[k * 9] + Bm[j];
            #pragma unroll
            for (int m = 1; m < 9; ++m)
                v = fmaxf(v, A[k * 9 + m] + Bm[m * 9 + j]);
            tree[doff + s * 81 + o] = v;
        }
        int tmp = soff; soff = doff; doff = tmp;
        __syncthreads();
    }
    if (tid < kK) {
        int k = tid;
        float fv = tree[soff + k * 9 + kSTART];
        #pragma unroll
        for (int j = 0; j < 9; ++j)
            if (j != kSTART) fv = fmaxf(fv, tree[soff + k * 9 + j] - 10000.f);
        red[k] = fv + trs[kSTOP * 9 + k];
    }
    __syncthreads();
    if (tid == 0) {
        float m = red[0];
        #pragma unroll
        for (int k = 1; k < 9; ++k) m = fmaxf(m, red[k]);
        out[b] = m;
    }
}

// ---------------------------------------------------------------------------
extern "C" void kernel_launch(void* const* d_in, const int* in_sizes, int n_in,
                              void* d_out, int out_size, void* d_ws, size_t ws_size,
                              hipStream_t stream) {
    const int*   sentence = (const int*)d_in[0];
    const int*   lengths  = (const int*)d_in[1];
    const float* emb      = (const float*)d_in[2];
    const float* Wih_f    = (const float*)d_in[3];
    const float* Whh_f    = (const float*)d_in[4];
    const float* b_f      = (const float*)d_in[5];
    const float* Wih_b    = (const float*)d_in[6];
    const float* Whh_b    = (const float*)d_in[7];
    const float* b_b      = (const float*)d_in[8];
    const float* Wt       = (const float*)d_in[9];
    const float* bt       = (const float*)d_in[10];
    const float* trans    = (const float*)d_in[11];
    float* out = (float*)d_out;

    char* ws = (char*)d_ws;
    const size_t gi_bytes = (size_t)2 * kB * kT * kG * sizeof(_Float16); // 128 MiB
    _Float16* gi   = (_Float16*)ws;
    _Float16* hws  = (_Float16*)ws;                  // aliases gi row heads
    float*    fsum = (float*)(ws + gi_bytes);        // 2.25 MiB

    proj_kernel<<<512, 256, 0, stream>>>(sentence, lengths, emb,
                                         Wih_f, b_f, Wih_b, b_b, gi);
    lstm_kernel<<<16, 512, 0, stream>>>(gi, hws, lengths, Whh_f, Whh_b);
    feats_kernel<<<4096, 256, 0, stream>>>(hws, Wt, bt, fsum);
    viterbi_kernel<<<128, 512, 0, stream>>>(lengths, trans, fsum, out);
}